// Round 8
// baseline (283.874 us; speedup 1.0000x reference)
//
#include <hip/hip_runtime.h>
#include <stdint.h>

#define Bb 8
#define Nn 1024
#define Dd 768
#define Hh 12
#define HDd 64
#define Mm (Bb * Nn)      // 8192
#define QKVN (3 * Dd)     // 2304
#define SCALE_F 8.0f      // sqrt(64), multiplies (no softmax in reference)

typedef __attribute__((ext_vector_type(8))) short bf16x8;
typedef __attribute__((ext_vector_type(4))) float f32x4;

__device__ __forceinline__ float bf2f(unsigned short u) {
  unsigned int v = ((unsigned int)u) << 16;
  float f;
  __builtin_memcpy(&f, &v, 4);
  return f;
}
__device__ __forceinline__ unsigned short f2bf(float f) {
  unsigned int u;
  __builtin_memcpy(&u, &f, 4);
  u += 0x7FFFu + ((u >> 16) & 1u);  // round-to-nearest-even
  return (unsigned short)(u >> 16);
}

#define GLDS16(g, l)                                                          \
  __builtin_amdgcn_global_load_lds(                                          \
      (const __attribute__((address_space(1))) void*)(g),                    \
      (__attribute__((address_space(3))) void*)(l), 16, 0, 0)

// ---------------- f32 -> bf16 convert (x, w_qkv, w_fc) ----------------
__global__ void convert_kernel(const float* __restrict__ x,
                               const float* __restrict__ wqkv,
                               const float* __restrict__ wfc,
                               unsigned short* __restrict__ xb,
                               unsigned short* __restrict__ wqkvb,
                               unsigned short* __restrict__ wfcb) {
  const int n1 = Mm * Dd / 4, n2 = QKVN * Dd / 4, n3 = Dd * Dd / 4;
  const int total = n1 + n2 + n3;
  for (int i = blockIdx.x * blockDim.x + threadIdx.x; i < total;
       i += gridDim.x * blockDim.x) {
    const float* src;
    unsigned short* dst;
    int j;
    if (i < n1) {
      src = x; dst = xb; j = i;
    } else if (i < n1 + n2) {
      src = wqkv; dst = wqkvb; j = i - n1;
    } else {
      src = wfc; dst = wfcb; j = i - n1 - n2;
    }
    const float4 v = ((const float4*)src)[j];
    ushort4 o;
    o.x = f2bf(v.x); o.y = f2bf(v.y); o.z = f2bf(v.z); o.w = f2bf(v.w);
    ((ushort4*)dst)[j] = o;
  }
}

// -------- BMx128 GEMM: C = A * B^T (+bias), occupancy-first ----------
// BK=64, 256 threads (4 waves, 2x2 wave grid; each wave (BM/2)x64).
// Single-buffered LDS, (256,5) -> up to 5 blocks/CU (TLP hides latency).
// XOR-swizzle via pre-swizzled global source (0 conflicts, verified).
// Requires gridDim.x*y*z % 8 == 0 (bijective chunked XCD remap).
template <int BM, bool BF16OUT>
__global__ __launch_bounds__(256, 5) void gemmk(
    const unsigned short* __restrict__ A, int lda, size_t aBatch,
    const unsigned short* __restrict__ Bm, int ldb, size_t bBatch,
    void* __restrict__ Cout, int ldc, size_t cBatch,
    const float* __restrict__ bias, int K) {
  constexpr int MI = BM / 32;           // 16-row frags per wave (m dim)
  constexpr int ACH = BM / 32;          // A staging chunks per wave
  __shared__ unsigned short lds[(BM + 128) * 64];
  const int tid = threadIdx.x;
  const int lane = tid & 63, w = tid >> 6;

  // ---- bijective chunked XCD remap, x-fastest decode ----
  const int gx = gridDim.x, gy = gridDim.y;
  int lid = blockIdx.x + gx * (blockIdx.y + gy * blockIdx.z);
  const int nwg = gx * gy * (int)gridDim.z;
  const int qch = nwg >> 3;
  lid = (lid & 7) * qch + (lid >> 3);
  const int bx = lid % gx;
  const int rem = lid / gx;
  const int by = rem % gy;
  const int bz = rem / gy;

  const int m0 = by * BM, n0 = bx * 128;
  const unsigned short* Aptr = A + (size_t)bz * aBatch;
  const unsigned short* Bptr = Bm + (size_t)bz * bBatch;

  const int lr = lane >> 3, lc = lane & 7;
  const int csw = (lc ^ lr) << 3;  // inverse-swizzled source col (elems)
  const int wr = w >> 1, wc = w & 1;
  const int fr = lane & 15, fk = lane >> 4;
  const int nt = K >> 6;  // 12

  f32x4 acc[MI][4] = {};

  for (int t = 0; t < nt; ++t) {
    const int k0 = t << 6;
    // ---- stage A (BMx64) and B (128x64) tiles, 1KB chunks ----
#pragma unroll
    for (int l = 0; l < ACH; ++l) {
      const int c = w * ACH + l;
      GLDS16(Aptr + (size_t)(m0 + c * 8 + lr) * lda + k0 + csw,
             &lds[c * 512]);
    }
#pragma unroll
    for (int l = 0; l < 4; ++l) {
      const int c = w * 4 + l;
      GLDS16(Bptr + (size_t)(n0 + c * 8 + lr) * ldb + k0 + csw,
             &lds[BM * 64 + c * 512]);
    }
    __syncthreads();  // drains vmcnt -> tile resident

    // ---- compute: 2 ks halves, frags re-read per half ----
#pragma unroll
    for (int ks = 0; ks < 2; ++ks) {
      bf16x8 af[MI], bf[4];
#pragma unroll
      for (int mi = 0; mi < MI; ++mi) {
        const int row = wr * (BM / 2) + mi * 16 + fr;
        af[mi] = *(const bf16x8*)&lds[row * 64 +
                                      ((ks * 32 + fk * 8) ^ ((row & 7) << 3))];
      }
#pragma unroll
      for (int ni = 0; ni < 4; ++ni) {
        const int row = wc * 64 + ni * 16 + fr;
        bf[ni] = *(const bf16x8*)&lds[BM * 64 + row * 64 +
                                      ((ks * 32 + fk * 8) ^ ((row & 7) << 3))];
      }
      __builtin_amdgcn_s_setprio(1);
#pragma unroll
      for (int mi = 0; mi < MI; ++mi)
#pragma unroll
        for (int ni = 0; ni < 4; ++ni)
          acc[mi][ni] = __builtin_amdgcn_mfma_f32_16x16x32_bf16(
              af[mi], bf[ni], acc[mi][ni], 0, 0, 0);
      __builtin_amdgcn_s_setprio(0);
    }
    __syncthreads();  // all reads done before next stage overwrites
  }

  // ---- epilogue ----
#pragma unroll
  for (int mi = 0; mi < MI; ++mi) {
#pragma unroll
    for (int ni = 0; ni < 4; ++ni) {
      const int col = n0 + wc * 64 + ni * 16 + fr;
      float bv = 0.0f;
      if (!BF16OUT) bv = bias[col];
#pragma unroll
      for (int r = 0; r < 4; ++r) {
        const int row = m0 + wr * (BM / 2) + mi * 16 + fk * 4 + r;
        const float val = acc[mi][ni][r] + bv;
        if (BF16OUT)
          ((unsigned short*)Cout + (size_t)bz * cBatch)
              [(size_t)row * ldc + col] = f2bf(val);
        else
          ((float*)Cout + (size_t)bz * cBatch)
              [(size_t)row * ldc + col] = val;
      }
    }
  }
}

// -------- kTv partials: part[c][bh][e][d] = sum_{j in chunk c} v*k ------
// grid (chunk=8, bh=96), 256 threads. No atomics: each block owns its slab.
__global__ __launch_bounds__(256) void ktv_kernel(
    const unsigned short* __restrict__ qkv, float* __restrict__ part) {
  __shared__ unsigned short kls[128 * 64];
  __shared__ unsigned short vls[128 * 64];
  const int bh = blockIdx.y;
  const int bb = bh / Hh, h = bh % Hh;
  const int chunk = blockIdx.x;
  const int j0 = chunk * 128;
  const int tid = threadIdx.x, lane = tid & 63, w = tid >> 6;
  const size_t rowbase = (size_t)(bb * Nn + j0);
#pragma unroll
  for (int i = 0; i < 4; ++i) {
    const int c = w * 4 + i;
    const int row = c * 8 + (lane >> 3);
    const int col = (lane & 7) * 8;
    const size_t g = (rowbase + row) * QKVN + h * HDd + col;
    GLDS16(qkv + g + Dd, &kls[c * 512]);       // k slice
    GLDS16(qkv + g + 2 * Dd, &vls[c * 512]);   // v slice
  }
  asm volatile("s_waitcnt vmcnt(0)" ::: "memory");
  __syncthreads();

  const int e0 = (tid >> 4) * 4, d0 = (tid & 15) * 4;
  float acc[4][4] = {};
#pragma unroll 4
  for (int j = 0; j < 128; ++j) {
    const ushort4 kv = *(const ushort4*)&kls[j * 64 + d0];
    const ushort4 vv = *(const ushort4*)&vls[j * 64 + e0];
    const float kf[4] = {bf2f(kv.x), bf2f(kv.y), bf2f(kv.z), bf2f(kv.w)};
    const float vf[4] = {bf2f(vv.x), bf2f(vv.y), bf2f(vv.z), bf2f(vv.w)};
#pragma unroll
    for (int e = 0; e < 4; ++e)
#pragma unroll
      for (int d = 0; d < 4; ++d) acc[e][d] += vf[e] * kf[d];
  }
  float* outp = part + ((size_t)chunk * 96 + bh) * 4096;
#pragma unroll
  for (int e = 0; e < 4; ++e)
#pragma unroll
    for (int d = 0; d < 4; ++d)
      outp[(e0 + e) * HDd + (d0 + d)] = acc[e][d];
}

// ------- W2T[b][e'][h*64+d] = SCALE * sum_e wfc[e'][h*64+e]*ktv[bh][e][d]
// Sums the 8 j-chunk partials while staging. grid (h=12, b=8), 512 thr.
__global__ __launch_bounds__(512) void w2_kernel(
    const float* __restrict__ part, const unsigned short* __restrict__ wfcb,
    unsigned short* __restrict__ w2t) {
  __shared__ unsigned short bt[64 * 72];  // [d][e], e-contiguous, pad to 72
  const int h = blockIdx.x, b = blockIdx.y;
  const int tid = threadIdx.x, lane = tid & 63, w = tid >> 6;
  const float* kp = part + (size_t)(b * Hh + h) * 4096;
  for (int i = tid; i < 4096; i += 512) {
    float s = 0.0f;
#pragma unroll
    for (int cc = 0; cc < 8; ++cc) s += kp[(size_t)cc * 96 * 4096 + i];
    const int e = i >> 6, d = i & 63;
    bt[d * 72 + e] = f2bf(s * SCALE_F);
  }
  __syncthreads();
  const int fr = lane & 15, fk = lane >> 4;
  bf16x8 bfr[4][2];
#pragma unroll
  for (int ni = 0; ni < 4; ++ni)
#pragma unroll
    for (int ks = 0; ks < 2; ++ks)
      bfr[ni][ks] =
          *(const bf16x8*)&bt[(ni * 16 + fr) * 72 + ks * 32 + fk * 8];
  f32x4 acc[6][4] = {};
#pragma unroll
  for (int mi = 0; mi < 6; ++mi) {
    const int ep = w * 96 + mi * 16 + fr;
#pragma unroll
    for (int ks = 0; ks < 2; ++ks) {
      const bf16x8 af = *(const bf16x8*)&wfcb[(size_t)ep * Dd + h * HDd +
                                              ks * 32 + fk * 8];
#pragma unroll
      for (int ni = 0; ni < 4; ++ni)
        acc[mi][ni] = __builtin_amdgcn_mfma_f32_16x16x32_bf16(
            af, bfr[ni][ks], acc[mi][ni], 0, 0, 0);
    }
  }
  unsigned short* op = w2t + (size_t)b * Dd * Dd + h * HDd;
#pragma unroll
  for (int mi = 0; mi < 6; ++mi)
#pragma unroll
    for (int ni = 0; ni < 4; ++ni) {
      const int d = ni * 16 + fr;
      const int ep = w * 96 + mi * 16 + fk * 4;
#pragma unroll
      for (int r = 0; r < 4; ++r)
        op[(size_t)(ep + r) * Dd + d] = f2bf(acc[mi][ni][r]);
    }
}

extern "C" void kernel_launch(void* const* d_in, const int* in_sizes, int n_in,
                              void* d_out, int out_size, void* d_ws,
                              size_t ws_size, hipStream_t stream) {
  const float* x = (const float*)d_in[0];
  const float* wqkv = (const float*)d_in[1];
  const float* wfc = (const float*)d_in[2];
  const float* bfc = (const float*)d_in[3];
  float* out = (float*)d_out;

  char* ws = (char*)d_ws;
  unsigned short* xb    = (unsigned short*)(ws);                // 12.6 MB
  float*          part  = (float*)(ws);      // aliases xb (dead after gemm1)
  unsigned short* wqkvb = (unsigned short*)(ws + 12582912);     // 3.5 MB
  unsigned short* wfcb  = (unsigned short*)(ws + 16121856);     // 1.2 MB
  unsigned short* qkv   = (unsigned short*)(ws + 17301504);     // 37.7 MB
  unsigned short* w2t   = (unsigned short*)(ws + 56623104);     // 9.4 MB
  // total 66,060,288 bytes

  convert_kernel<<<2112, 256, 0, stream>>>(x, wqkv, wfc, xb, wqkvb, wfcb);
  // qkv = x * wqkv^T : M=8192, N=2304, K=768  (grid 18*64 = 1152, %8==0)
  gemmk<128, true><<<dim3(QKVN / 128, Mm / 128, 1), 256, 0, stream>>>(
      xb, Dd, 0, wqkvb, Dd, 0, qkv, QKVN, 0, nullptr, Dd);
  // part[c][bh] = per-chunk K^T V partials (xb is dead; reuse its space)
  ktv_kernel<<<dim3(8, 96), 256, 0, stream>>>(qkv, part);
  w2_kernel<<<dim3(Hh, Bb), 512, 0, stream>>>(part, wfcb, w2t);
  // out[b] = q[b] * W2T[b]^T + bias : per-batch M=1024, N=768, K=768
  // (grid 6*16*8 = 768, %8==0; BM=64 doubles block parallelism)
  gemmk<64, false><<<dim3(Dd / 128, Nn / 64, Bb), 256, 0, stream>>>(
      qkv, QKVN, (size_t)Nn * QKVN, w2t, Dd, (size_t)Dd * Dd, out, Dd,
      (size_t)Nn * Dd, bfc, Dd);
}

// Round 9
// 95.195 us; speedup vs baseline: 2.9820x; 2.9820x over previous
//
#include <hip/hip_runtime.h>
#include <stdint.h>

#define Bb 8
#define Nn 1024
#define Dd 768
#define Hh 12
#define HDd 64
#define Mm (Bb * Nn)      // 8192
#define QKVN (3 * Dd)     // 2304
#define SCALE_F 8.0f      // sqrt(64), multiplies (no softmax in reference)

typedef __attribute__((ext_vector_type(8))) short bf16x8;
typedef __attribute__((ext_vector_type(4))) float f32x4;

__device__ __forceinline__ float bf2f(unsigned short u) {
  unsigned int v = ((unsigned int)u) << 16;
  float f;
  __builtin_memcpy(&f, &v, 4);
  return f;
}
__device__ __forceinline__ unsigned short f2bf(float f) {
  unsigned int u;
  __builtin_memcpy(&u, &f, 4);
  u += 0x7FFFu + ((u >> 16) & 1u);  // round-to-nearest-even
  return (unsigned short)(u >> 16);
}

#define GLDS16(g, l)                                                          \
  __builtin_amdgcn_global_load_lds(                                          \
      (const __attribute__((address_space(1))) void*)(g),                    \
      (__attribute__((address_space(3))) void*)(l), 16, 0, 0)

// ---------------- f32 -> bf16 convert (x, w_qkv, w_fc) ----------------
__global__ void convert_kernel(const float* __restrict__ x,
                               const float* __restrict__ wqkv,
                               const float* __restrict__ wfc,
                               unsigned short* __restrict__ xb,
                               unsigned short* __restrict__ wqkvb,
                               unsigned short* __restrict__ wfcb) {
  const int n1 = Mm * Dd / 4, n2 = QKVN * Dd / 4, n3 = Dd * Dd / 4;
  const int total = n1 + n2 + n3;
  for (int i = blockIdx.x * blockDim.x + threadIdx.x; i < total;
       i += gridDim.x * blockDim.x) {
    const float* src;
    unsigned short* dst;
    int j;
    if (i < n1) {
      src = x; dst = xb; j = i;
    } else if (i < n1 + n2) {
      src = wqkv; dst = wqkvb; j = i - n1;
    } else {
      src = wfc; dst = wfcb; j = i - n1 - n2;
    }
    const float4 v = ((const float4*)src)[j];
    ushort4 o;
    o.x = f2bf(v.x); o.y = f2bf(v.y); o.z = f2bf(v.z); o.w = f2bf(v.w);
    ((ushort4*)dst)[j] = o;
  }
}

// -------- BMx128 GEMM: C = A * B^T (+bias), occupancy-first ----------
// BK=64, 256 threads (4 waves, 2x2 wave grid; each wave (BM/2)x64).
// Single-buffered LDS; (256,4) — R8 showed (256,5) caps VGPR at 48 and
// spills the accumulators (FETCH 35->300 MB, 6x slower). LDS is the
// occupancy limiter (32KB -> 5 blocks/CU; 24KB -> 6), not VGPRs.
// XOR-swizzle via pre-swizzled global source (0 conflicts, verified).
// Requires gridDim.x*y*z % 8 == 0 (bijective chunked XCD remap).
template <int BM, bool BF16OUT>
__global__ __launch_bounds__(256, 4) void gemmk(
    const unsigned short* __restrict__ A, int lda, size_t aBatch,
    const unsigned short* __restrict__ Bm, int ldb, size_t bBatch,
    void* __restrict__ Cout, int ldc, size_t cBatch,
    const float* __restrict__ bias, int K) {
  constexpr int MI = BM / 32;           // 16-row frags per wave (m dim)
  constexpr int ACH = BM / 32;          // A staging chunks per wave
  __shared__ unsigned short lds[(BM + 128) * 64];
  const int tid = threadIdx.x;
  const int lane = tid & 63, w = tid >> 6;

  // ---- bijective chunked XCD remap, x-fastest decode ----
  const int gx = gridDim.x, gy = gridDim.y;
  int lid = blockIdx.x + gx * (blockIdx.y + gy * blockIdx.z);
  const int nwg = gx * gy * (int)gridDim.z;
  const int qch = nwg >> 3;
  lid = (lid & 7) * qch + (lid >> 3);
  const int bx = lid % gx;
  const int rem = lid / gx;
  const int by = rem % gy;
  const int bz = rem / gy;

  const int m0 = by * BM, n0 = bx * 128;
  const unsigned short* Aptr = A + (size_t)bz * aBatch;
  const unsigned short* Bptr = Bm + (size_t)bz * bBatch;

  const int lr = lane >> 3, lc = lane & 7;
  const int csw = (lc ^ lr) << 3;  // inverse-swizzled source col (elems)
  const int wr = w >> 1, wc = w & 1;
  const int fr = lane & 15, fk = lane >> 4;
  const int nt = K >> 6;  // 12

  f32x4 acc[MI][4] = {};

  for (int t = 0; t < nt; ++t) {
    const int k0 = t << 6;
    // ---- stage A (BMx64) and B (128x64) tiles, 1KB chunks ----
#pragma unroll
    for (int l = 0; l < ACH; ++l) {
      const int c = w * ACH + l;
      GLDS16(Aptr + (size_t)(m0 + c * 8 + lr) * lda + k0 + csw,
             &lds[c * 512]);
    }
#pragma unroll
    for (int l = 0; l < 4; ++l) {
      const int c = w * 4 + l;
      GLDS16(Bptr + (size_t)(n0 + c * 8 + lr) * ldb + k0 + csw,
             &lds[BM * 64 + c * 512]);
    }
    __syncthreads();  // drains vmcnt -> tile resident

    // ---- compute: 2 ks halves, frags re-read per half ----
#pragma unroll
    for (int ks = 0; ks < 2; ++ks) {
      bf16x8 af[MI], bf[4];
#pragma unroll
      for (int mi = 0; mi < MI; ++mi) {
        const int row = wr * (BM / 2) + mi * 16 + fr;
        af[mi] = *(const bf16x8*)&lds[row * 64 +
                                      ((ks * 32 + fk * 8) ^ ((row & 7) << 3))];
      }
#pragma unroll
      for (int ni = 0; ni < 4; ++ni) {
        const int row = wc * 64 + ni * 16 + fr;
        bf[ni] = *(const bf16x8*)&lds[BM * 64 + row * 64 +
                                      ((ks * 32 + fk * 8) ^ ((row & 7) << 3))];
      }
      __builtin_amdgcn_s_setprio(1);
#pragma unroll
      for (int mi = 0; mi < MI; ++mi)
#pragma unroll
        for (int ni = 0; ni < 4; ++ni)
          acc[mi][ni] = __builtin_amdgcn_mfma_f32_16x16x32_bf16(
              af[mi], bf[ni], acc[mi][ni], 0, 0, 0);
      __builtin_amdgcn_s_setprio(0);
    }
    __syncthreads();  // all reads done before next stage overwrites
  }

  // ---- epilogue ----
#pragma unroll
  for (int mi = 0; mi < MI; ++mi) {
#pragma unroll
    for (int ni = 0; ni < 4; ++ni) {
      const int col = n0 + wc * 64 + ni * 16 + fr;
      float bv = 0.0f;
      if (!BF16OUT) bv = bias[col];
#pragma unroll
      for (int r = 0; r < 4; ++r) {
        const int row = m0 + wr * (BM / 2) + mi * 16 + fk * 4 + r;
        const float val = acc[mi][ni][r] + bv;
        if (BF16OUT)
          ((unsigned short*)Cout + (size_t)bz * cBatch)
              [(size_t)row * ldc + col] = f2bf(val);
        else
          ((float*)Cout + (size_t)bz * cBatch)
              [(size_t)row * ldc + col] = val;
      }
    }
  }
}

// -------- kTv partials: part[c][bh][e][d] = sum_{j in chunk c} v*k ------
// grid (chunk=8, bh=96), 256 threads. No atomics: each block owns its slab.
__global__ __launch_bounds__(256) void ktv_kernel(
    const unsigned short* __restrict__ qkv, float* __restrict__ part) {
  __shared__ unsigned short kls[128 * 64];
  __shared__ unsigned short vls[128 * 64];
  const int bh = blockIdx.y;
  const int bb = bh / Hh, h = bh % Hh;
  const int chunk = blockIdx.x;
  const int j0 = chunk * 128;
  const int tid = threadIdx.x, lane = tid & 63, w = tid >> 6;
  const size_t rowbase = (size_t)(bb * Nn + j0);
#pragma unroll
  for (int i = 0; i < 4; ++i) {
    const int c = w * 4 + i;
    const int row = c * 8 + (lane >> 3);
    const int col = (lane & 7) * 8;
    const size_t g = (rowbase + row) * QKVN + h * HDd + col;
    GLDS16(qkv + g + Dd, &kls[c * 512]);       // k slice
    GLDS16(qkv + g + 2 * Dd, &vls[c * 512]);   // v slice
  }
  asm volatile("s_waitcnt vmcnt(0)" ::: "memory");
  __syncthreads();

  const int e0 = (tid >> 4) * 4, d0 = (tid & 15) * 4;
  float acc[4][4] = {};
#pragma unroll 4
  for (int j = 0; j < 128; ++j) {
    const ushort4 kv = *(const ushort4*)&kls[j * 64 + d0];
    const ushort4 vv = *(const ushort4*)&vls[j * 64 + e0];
    const float kf[4] = {bf2f(kv.x), bf2f(kv.y), bf2f(kv.z), bf2f(kv.w)};
    const float vf[4] = {bf2f(vv.x), bf2f(vv.y), bf2f(vv.z), bf2f(vv.w)};
#pragma unroll
    for (int e = 0; e < 4; ++e)
#pragma unroll
      for (int d = 0; d < 4; ++d) acc[e][d] += vf[e] * kf[d];
  }
  float* outp = part + ((size_t)chunk * 96 + bh) * 4096;
#pragma unroll
  for (int e = 0; e < 4; ++e)
#pragma unroll
    for (int d = 0; d < 4; ++d)
      outp[(e0 + e) * HDd + (d0 + d)] = acc[e][d];
}

// ------- W2T[b][e'][h*64+d] = SCALE * sum_e wfc[e'][h*64+e]*ktv[bh][e][d]
// Sums the 8 j-chunk partials while staging. grid (h=12, b=8), 512 thr.
__global__ __launch_bounds__(512) void w2_kernel(
    const float* __restrict__ part, const unsigned short* __restrict__ wfcb,
    unsigned short* __restrict__ w2t) {
  __shared__ unsigned short bt[64 * 72];  // [d][e], e-contiguous, pad to 72
  const int h = blockIdx.x, b = blockIdx.y;
  const int tid = threadIdx.x, lane = tid & 63, w = tid >> 6;
  const float* kp = part + (size_t)(b * Hh + h) * 4096;
  for (int i = tid; i < 4096; i += 512) {
    float s = 0.0f;
#pragma unroll
    for (int cc = 0; cc < 8; ++cc) s += kp[(size_t)cc * 96 * 4096 + i];
    const int e = i >> 6, d = i & 63;
    bt[d * 72 + e] = f2bf(s * SCALE_F);
  }
  __syncthreads();
  const int fr = lane & 15, fk = lane >> 4;
  bf16x8 bfr[4][2];
#pragma unroll
  for (int ni = 0; ni < 4; ++ni)
#pragma unroll
    for (int ks = 0; ks < 2; ++ks)
      bfr[ni][ks] =
          *(const bf16x8*)&bt[(ni * 16 + fr) * 72 + ks * 32 + fk * 8];
  f32x4 acc[6][4] = {};
#pragma unroll
  for (int mi = 0; mi < 6; ++mi) {
    const int ep = w * 96 + mi * 16 + fr;
#pragma unroll
    for (int ks = 0; ks < 2; ++ks) {
      const bf16x8 af = *(const bf16x8*)&wfcb[(size_t)ep * Dd + h * HDd +
                                              ks * 32 + fk * 8];
#pragma unroll
      for (int ni = 0; ni < 4; ++ni)
        acc[mi][ni] = __builtin_amdgcn_mfma_f32_16x16x32_bf16(
            af, bfr[ni][ks], acc[mi][ni], 0, 0, 0);
    }
  }
  unsigned short* op = w2t + (size_t)b * Dd * Dd + h * HDd;
#pragma unroll
  for (int mi = 0; mi < 6; ++mi)
#pragma unroll
    for (int ni = 0; ni < 4; ++ni) {
      const int d = ni * 16 + fr;
      const int ep = w * 96 + mi * 16 + fk * 4;
#pragma unroll
      for (int r = 0; r < 4; ++r)
        op[(size_t)(ep + r) * Dd + d] = f2bf(acc[mi][ni][r]);
    }
}

extern "C" void kernel_launch(void* const* d_in, const int* in_sizes, int n_in,
                              void* d_out, int out_size, void* d_ws,
                              size_t ws_size, hipStream_t stream) {
  const float* x = (const float*)d_in[0];
  const float* wqkv = (const float*)d_in[1];
  const float* wfc = (const float*)d_in[2];
  const float* bfc = (const float*)d_in[3];
  float* out = (float*)d_out;

  char* ws = (char*)d_ws;
  unsigned short* xb    = (unsigned short*)(ws);                // 12.6 MB
  float*          part  = (float*)(ws);      // aliases xb (dead after gemm1)
  unsigned short* wqkvb = (unsigned short*)(ws + 12582912);     // 3.5 MB
  unsigned short* wfcb  = (unsigned short*)(ws + 16121856);     // 1.2 MB
  unsigned short* qkv   = (unsigned short*)(ws + 17301504);     // 37.7 MB
  unsigned short* w2t   = (unsigned short*)(ws + 56623104);     // 9.4 MB
  // total 66,060,288 bytes

  convert_kernel<<<2112, 256, 0, stream>>>(x, wqkv, wfc, xb, wqkvb, wfcb);
  // qkv = x * wqkv^T : M=8192, N=2304, K=768  (grid 18*64 = 1152, %8==0)
  gemmk<128, true><<<dim3(QKVN / 128, Mm / 128, 1), 256, 0, stream>>>(
      xb, Dd, 0, wqkvb, Dd, 0, qkv, QKVN, 0, nullptr, Dd);
  // part[c][bh] = per-chunk K^T V partials (xb is dead; reuse its space)
  ktv_kernel<<<dim3(8, 96), 256, 0, stream>>>(qkv, part);
  w2_kernel<<<dim3(Hh, Bb), 512, 0, stream>>>(part, wfcb, w2t);
  // out[b] = q[b] * W2T[b]^T + bias : per-batch M=1024, N=768, K=768
  // (grid 6*16*8 = 768, %8==0; BM=64 doubles block parallelism)
  gemmk<64, false><<<dim3(Dd / 128, Nn / 64, Bb), 256, 0, stream>>>(
      qkv, QKVN, (size_t)Nn * QKVN, w2t, Dd, (size_t)Dd * Dd, out, Dd,
      (size_t)Nn * Dd, bfc, Dd);
}